// Round 15
// baseline (352.841 us; speedup 1.0000x reference)
//
#include <hip/hip_runtime.h>
#include <hip/hip_bf16.h>
#include <math.h>

// ---------------------------------------------------------------------------
// MHA: out = softmax((q@Wq+bq)(k@Wk+bk)^T / sqrt(dk)) (v@Wv+bv) @ Wo + bo
// B=8 H=8 L=2048 D=128.  Pipeline:
//   cast(f32->bf16, W transposed, log2e/sqrt(128) folded into Wq/bq)
//   -> fused QKV projection GEMM (3072 blocks, z selects; r14)
//   -> flash attention v15: FAT WAVES AT 2 WAVES/SIMD.  4 waves x 64q,
//      KVBLK=64, K+V dbuf (64KB) + per-qf 2KB P round-trip (r8 pattern) =
//      72KB LDS -> 2 blocks/CU; (256,2) -> 256-VGPR cap, kernel ~196.
//      K/V LDS bytes amortized over 64 q (256 B/MFMA, half of r8).
//      [r9's q_w=64 failed only because 96KB LDS -> 1 blk/CU -> 1 wave/SIMD]
//   -> out-proj GEMM (512 blocks; r13)
// [Session laws: launch_bounds 2nd arg X => X waves/EU residency AND VGPR
//  cap (X=1:~512, X=2:256, X=4:64).  Regressions: r6 kv-split, r7 V-from-
//  global, r9 fat-waves@1w/SIMD, r10/r11 KVBLK=32, r12 counted vmcnt.]
// ---------------------------------------------------------------------------

typedef __attribute__((ext_vector_type(8))) short s16x8;   // 8 bf16
typedef __attribute__((ext_vector_type(4))) short s16x4;   // 4 bf16
typedef __attribute__((ext_vector_type(4))) float f32x4;

#define MFMA16(a, b, c) __builtin_amdgcn_mfma_f32_16x16x32_bf16((a), (b), (c), 0, 0, 0)

static constexpr int HN = 8, LN = 2048;
static constexpr int MROWS = 16384;

static __device__ __forceinline__ unsigned short f2b(float f) {
  __hip_bfloat16 h = __float2bfloat16(f);
  union { __hip_bfloat16 h; unsigned short u; } cv;
  cv.h = h;
  return cv.u;
}

static __device__ __forceinline__ s16x8 ld16(const void* p) {
  uint4 t = *(const uint4*)p;
  return __builtin_bit_cast(s16x8, t);
}

// async global->LDS, 16B per lane; LDS dest = wave-uniform base + lane*16
static __device__ __forceinline__ void gload16(const void* g, void* l) {
  __builtin_amdgcn_global_load_lds(
      (const __attribute__((address_space(1))) unsigned int*)g,
      (__attribute__((address_space(3))) unsigned int*)l, 16, 0, 0);
}

static __device__ __forceinline__ unsigned cvt_pk(float lo, float hi) {
  unsigned r;                       // r = [bf16(lo) | bf16(hi)<<16]
  asm("v_cvt_pk_bf16_f32 %0, %1, %2" : "=v"(r) : "v"(lo), "v"(hi));
  return r;
}

static __device__ __forceinline__ float fexp2(float x) {
  float r;
  asm("v_exp_f32 %0, %1" : "=v"(r) : "v"(x));
  return r;
}

// ---------------------------------------------------------------------------
// Kernel 1: casts + weight transposes (unchanged).
// ---------------------------------------------------------------------------
__global__ __launch_bounds__(256) void cast_kernel(
    const float* __restrict__ q, const float* __restrict__ k,
    const float* __restrict__ v, const float* __restrict__ Wq,
    const float* __restrict__ Wk, const float* __restrict__ Wv,
    const float* __restrict__ Wo,
    __hip_bfloat16* __restrict__ qb, __hip_bfloat16* __restrict__ kb,
    __hip_bfloat16* __restrict__ vb, __hip_bfloat16* __restrict__ Wqt,
    __hip_bfloat16* __restrict__ Wkt, __hip_bfloat16* __restrict__ Wvt,
    __hip_bfloat16* __restrict__ Wot, float qscale)
{
  const int bid = blockIdx.x, tid = threadIdx.x;
  if (bid < 6144) {
    const int idx4 = bid * 256 + tid;
    const int arr  = idx4 >> 19;
    const int off4 = idx4 & ((1 << 19) - 1);
    const float* src = (arr == 0) ? q : (arr == 1) ? k : v;
    __hip_bfloat16* dst = (arr == 0) ? qb : (arr == 1) ? kb : vb;
    float4 ld = ((const float4*)src)[off4];
    s16x4 pk;
    pk[0] = (short)f2b(ld.x); pk[1] = (short)f2b(ld.y);
    pk[2] = (short)f2b(ld.z); pk[3] = (short)f2b(ld.w);
    ((s16x4*)dst)[off4] = pk;
  } else {
    const int t = (bid - 6144) * 256 + tid;
    const int which = t >> 17;
    const int i = t & ((1 << 17) - 1);
    if (which < 3) {
      const int n = i >> 7, kk = i & 127;
      const float* W = (which == 0) ? Wq : (which == 1) ? Wk : Wv;
      __hip_bfloat16* Wt = (which == 0) ? Wqt : (which == 1) ? Wkt : Wvt;
      float val = W[kk * 1024 + n];
      if (which == 0) val *= qscale;
      Wt[n * 128 + kk] = __float2bfloat16(val);
    } else {
      const int n = i >> 10, kk = i & 1023;
      Wot[n * 1024 + kk] = __float2bfloat16(Wo[kk * 128 + n]);
    }
  }
}

// ---------------------------------------------------------------------------
// Kernel 2a: fused QKV projection GEMM (one launch, blockIdx.z selects).
// ---------------------------------------------------------------------------
__global__ __launch_bounds__(256) void qkv_kernel(
    const __hip_bfloat16* __restrict__ qb, const __hip_bfloat16* __restrict__ kb,
    const __hip_bfloat16* __restrict__ vb,
    const __hip_bfloat16* __restrict__ Wqt, const __hip_bfloat16* __restrict__ Wkt,
    const __hip_bfloat16* __restrict__ Wvt,
    const float* __restrict__ bq, const float* __restrict__ bk,
    const float* __restrict__ bv,
    __hip_bfloat16* __restrict__ Qh, __hip_bfloat16* __restrict__ Kh,
    __hip_bfloat16* __restrict__ Vt, float qscale)
{
  constexpr int NF = 4, K = 128;
  constexpr int BUFB = (4 + NF) * 4096;        // A 16KB + B 16KB
  __shared__ char lds[2 * BUFB];

  const int z = blockIdx.z;
  const __hip_bfloat16* A   = (z == 0) ? qb  : (z == 1) ? kb  : vb;
  const __hip_bfloat16* Btr = (z == 0) ? Wqt : (z == 1) ? Wkt : Wvt;
  const float* bias         = (z == 0) ? bq  : (z == 1) ? bk  : bv;
  __hip_bfloat16* outp      = (z == 0) ? Qh  : (z == 1) ? Kh  : Vt;
  const float bias_scale    = (z == 0) ? qscale : 1.0f;
  const bool vmode          = (z == 2);

  const int tid = threadIdx.x;
  const int l = tid & 63, w = tid >> 6;        // 4 waves
  const int wr = w >> 1, wc = w & 1;
  const int m0 = blockIdx.x * 128, n0 = blockIdx.y * 128;
  const int cq = l & 15, rg = l >> 4;
  const int lrow8 = l >> 3, lcol8 = l & 7;
  const int swz8 = (lcol8 ^ lrow8) * 8;        // inverse-swizzle (elems)

  f32x4 acc[4][NF] = {};

  auto stage = [&](int bb, int k0) {
    char* Ab = lds + bb * BUFB;
    char* Bb = Ab + 16384;
#pragma unroll
    for (int c = 0; c < 4; ++c) {
      const int ca = w * 4 + c;
      gload16(A + (size_t)(m0 + ca * 8 + lrow8) * K + k0 + swz8, Ab + ca * 1024);
    }
#pragma unroll
    for (int c = 0; c < NF; ++c) {
      const int cb = w * NF + c;
      gload16(Btr + (size_t)(n0 + cb * 8 + lrow8) * K + k0 + swz8, Bb + cb * 1024);
    }
  };

  stage(0, 0);
  __syncthreads();

  for (int kt = 0; kt < 2; ++kt) {
    const int cur = kt & 1;
    if (kt == 0) stage(1, 64);
    char* As = lds + cur * BUFB;
    char* Bs = As + 16384;
#pragma unroll
    for (int ks = 0; ks < 2; ++ks) {
      s16x8 af[4], bf[NF];
#pragma unroll
      for (int mf = 0; mf < 4; ++mf) {
        const int arow = wr * 64 + mf * 16 + cq;
        af[mf] = ld16(As + arow * 128 + ((ks * 64 + rg * 16) ^ ((arow & 7) << 4)));
      }
#pragma unroll
      for (int nf = 0; nf < NF; ++nf) {
        const int brow = wc * (NF * 16) + nf * 16 + cq;
        bf[nf] = ld16(Bs + brow * 128 + ((ks * 64 + rg * 16) ^ ((brow & 7) << 4)));
      }
#pragma unroll
      for (int mf = 0; mf < 4; ++mf)
#pragma unroll
        for (int nf = 0; nf < NF; ++nf)
          acc[mf][nf] = MFMA16(af[mf], bf[nf], acc[mf][nf]);
    }
    __syncthreads();
  }

  // epilogue: C/D layout col = lane&15, row = (lane>>4)*4 + r
#pragma unroll
  for (int nf = 0; nf < NF; ++nf) {
    const int gn = n0 + wc * (NF * 16) + nf * 16 + cq;
    const float bv_ = bias[gn] * bias_scale;
    const int h = gn >> 7, d = gn & 127;
#pragma unroll
    for (int mf = 0; mf < 4; ++mf) {
      const int gm0 = m0 + wr * 64 + mf * 16 + rg * 4;
      const f32x4 a = acc[mf][nf];
      if (!vmode) {
#pragma unroll
        for (int r = 0; r < 4; ++r) {
          const int gm = gm0 + r;
          const int b = gm >> 11, lr = gm & (LN - 1);
          outp[((size_t)(b * HN + h) * LN + lr) * 128 + d] = __float2bfloat16(a[r] + bv_);
        }
      } else {
        const int b = gm0 >> 11, kv = gm0 & (LN - 1);
        s16x4 pk;
#pragma unroll
        for (int r = 0; r < 4; ++r) pk[r] = (short)f2b(a[r] + bv_);
        *(s16x4*)(outp + ((size_t)(b * HN + h) * 128 + d) * LN + kv) = pk;
      }
    }
  }
}

// ---------------------------------------------------------------------------
// Kernel 2b: out-proj GEMM  (unchanged from r13/r14).
// ---------------------------------------------------------------------------
__global__ __launch_bounds__(256) void oproj_kernel(
    const __hip_bfloat16* __restrict__ A, const __hip_bfloat16* __restrict__ Btr,
    const float* __restrict__ bias, float* __restrict__ outp, int K)
{
  constexpr int NF = 1;
  constexpr int BUFB = (4 + NF) * 4096;        // A 16KB + B 4KB
  __shared__ char lds[2 * BUFB];

  const int tid = threadIdx.x;
  const int l = tid & 63, w = tid >> 6;
  const int wr = w >> 1, wc = w & 1;
  const int m0 = blockIdx.x * 128, n0 = blockIdx.y * 32;
  const int cq = l & 15, rg = l >> 4;
  const int lrow8 = l >> 3, lcol8 = l & 7;
  const int swz8 = (lcol8 ^ lrow8) * 8;
  const int nk = K >> 6;

  f32x4 acc[4][NF] = {};

  auto stage = [&](int bb, int k0) {
    char* Ab = lds + bb * BUFB;
    char* Bb = Ab + 16384;
#pragma unroll
    for (int c = 0; c < 4; ++c) {
      const int ca = w * 4 + c;
      gload16(A + (size_t)(m0 + ca * 8 + lrow8) * K + k0 + swz8, Ab + ca * 1024);
    }
#pragma unroll
    for (int c = 0; c < NF; ++c) {
      const int cb = w * NF + c;
      gload16(Btr + (size_t)(n0 + cb * 8 + lrow8) * K + k0 + swz8, Bb + cb * 1024);
    }
  };

  stage(0, 0);
  __syncthreads();

  for (int kt = 0; kt < nk; ++kt) {
    const int cur = kt & 1;
    if (kt + 1 < nk) stage(cur ^ 1, (kt + 1) << 6);
    char* As = lds + cur * BUFB;
    char* Bs = As + 16384;
#pragma unroll
    for (int ks = 0; ks < 2; ++ks) {
      s16x8 af[4], bf[NF];
#pragma unroll
      for (int mf = 0; mf < 4; ++mf) {
        const int arow = wr * 64 + mf * 16 + cq;
        af[mf] = ld16(As + arow * 128 + ((ks * 64 + rg * 16) ^ ((arow & 7) << 4)));
      }
#pragma unroll
      for (int nf = 0; nf < NF; ++nf) {
        const int brow = wc * (NF * 16) + nf * 16 + cq;
        bf[nf] = ld16(Bs + brow * 128 + ((ks * 64 + rg * 16) ^ ((brow & 7) << 4)));
      }
#pragma unroll
      for (int mf = 0; mf < 4; ++mf)
#pragma unroll
        for (int nf = 0; nf < NF; ++nf)
          acc[mf][nf] = MFMA16(af[mf], bf[nf], acc[mf][nf]);
    }
    __syncthreads();
  }

#pragma unroll
  for (int nf = 0; nf < NF; ++nf) {
    const int gn = n0 + wc * (NF * 16) + nf * 16 + cq;
    const float bv_ = bias[gn];
#pragma unroll
    for (int mf = 0; mf < 4; ++mf) {
      const int gm0 = m0 + wr * 64 + mf * 16 + rg * 4;
      const f32x4 a = acc[mf][nf];
#pragma unroll
      for (int r = 0; r < 4; ++r)
        outp[(size_t)(gm0 + r) * 128 + gn] = a[r] + bv_;
    }
  }
}

// ---------------------------------------------------------------------------
// Kernel 3: flash attention v15 (fat waves at 2 waves/SIMD).
// Block = 4 waves (256 thr) = 256 q of one (b,h); wave = 64 q x KVBLK=64.
// launch_bounds(256,2): 256-VGPR cap, 2 blocks/CU (72KB LDS), 2 waves/SIMD.
// K [2][64][256B] + V^T [2][128][128B] dbuf via global_load_lds; per-qf
// 2KB wave-local P round-trip (r8 pattern x4).  K/V LDS reads amortized
// over 64 q/wave = 256 B/MFMA (half of r8).  Fixed-offset softmax.
// ---------------------------------------------------------------------------
__global__ __launch_bounds__(256, 2) void attn_kernel(
    const __hip_bfloat16* __restrict__ Qh, const __hip_bfloat16* __restrict__ Kh,
    const __hip_bfloat16* __restrict__ Vt, __hip_bfloat16* __restrict__ Obuf)
{
  __shared__ char lds[73728];          // K 2x16K | V 2x16K | P 4x2K
  char* Ks = lds;                      // [2][64 rows][256B]
  char* Vs = lds + 32768;              // [2][128 rows][128B]

  // bijective XCD swizzle: 512 blocks = 8 xcd x 8 bh x 8 qtiles
  const int x = blockIdx.x;
  const int xcd = x & 7, ii = x >> 3;
  const int bh = xcd * 8 + (ii >> 3);
  const int qt = ii & 7;

  const int tid = threadIdx.x, l = tid & 63, w = tid >> 6;   // w in [0,4)
  const int cq = l & 15, rg = l >> 4;
  const int q0 = qt * 256 + w * 64;

  char* Pw = lds + 65536 + w * 2048;   // per-wave P^T: [16 q][128B] (swz)

  const char* Qc = (const char*)(Qh + (size_t)bh * LN * 128);
  const char* Kc = (const char*)(Kh + (size_t)bh * LN * 128);
  const char* Vc = (const char*)(Vt + (size_t)bh * 128 * LN);

  // Q fragments in registers (B-operand of swapped QK^T): 4 q-frags
  s16x8 qreg[4][4];
#pragma unroll
  for (int qf = 0; qf < 4; ++qf)
#pragma unroll
    for (int ks = 0; ks < 4; ++ks)
      qreg[qf][ks] = ld16(Qc + (size_t)(q0 + qf * 16 + cq) * 256 + ks * 64 + rg * 16);

  // staging source offsets (inverse-swizzled); LDS dests linear (lane*16)
  int kgoff[4], vgoff[4];
#pragma unroll
  for (int j = 0; j < 4; ++j) {
    const int ck = w * 256 + j * 64 + l;               // chunk in [0,1024)
    const int kr = ck >> 4, kc = ck & 15;              // K: rows of 256B
    kgoff[j] = kr * 256 + ((kc ^ (kr & 7)) * 16);
    const int vr = ck >> 3, vc = ck & 7;               // V: rows of 128B
    vgoff[j] = vr * 4096 + ((vc ^ (vr & 7)) * 16);     // global row stride 4KB
  }

  auto stageKV = [&](int buf, int t) {
    const char* kg = Kc + (size_t)t * 16384;
    const char* vg = Vc + (size_t)t * 128;
#pragma unroll
    for (int j = 0; j < 4; ++j) {
      gload16(kg + kgoff[j], Ks + buf * 16384 + w * 4096 + j * 1024);
      gload16(vg + vgoff[j], Vs + buf * 16384 + w * 4096 + j * 1024);
    }
  };

  f32x4 acc[8][4] = {};
  float ls[4] = {0.f, 0.f, 0.f, 0.f};

  stageKV(0, 0);
  __syncthreads();

  const int prow = cq * 128;
  const int psw = (cq & 7) << 4;

  for (int t = 0; t < 32; ++t) {
    const int cur = t & 1;
    if (t < 31) stageKV(cur ^ 1, t + 1);          // async prefetch t+1
    char* Kb = Ks + cur * 16384;
    char* Vb = Vs + cur * 16384;

    // QK^T: st[qf][t4], kv = t4*16 + rg*4 + r, q = qf*16 + cq
    f32x4 st[4][4] = {};
    __builtin_amdgcn_s_setprio(1);
#pragma unroll
    for (int t4 = 0; t4 < 4; ++t4) {
      const int row = t4 * 16 + cq;
      const int rsw = (row & 7) << 4;
      s16x8 kf[4];
#pragma unroll
      for (int ks = 0; ks < 4; ++ks)
        kf[ks] = ld16(Kb + row * 256 + ((ks * 64 + rg * 16) ^ rsw));
#pragma unroll
      for (int ks = 0; ks < 4; ++ks)
#pragma unroll
        for (int qf = 0; qf < 4; ++qf)
          st[qf][t4] = MFMA16(kf[ks], qreg[qf][ks], st[qf][t4]);
    }
    __builtin_amdgcn_s_setprio(0);

    // P = exp2(S) per qf -> 2KB wave-local swizzled LDS round-trip (r8 x4)
    s16x8 pb[4][2];
#pragma unroll
    for (int qf = 0; qf < 4; ++qf) {
      float sum = 0.f;
#pragma unroll
      for (int t4 = 0; t4 < 4; ++t4) {
        const float e0 = fexp2(st[qf][t4][0]);
        const float e1 = fexp2(st[qf][t4][1]);
        const float e2 = fexp2(st[qf][t4][2]);
        const float e3 = fexp2(st[qf][t4][3]);
        sum += (e0 + e1) + (e2 + e3);
        uint2 pk;
        pk.x = cvt_pk(e0, e1);
        pk.y = cvt_pk(e2, e3);
        *(uint2*)(Pw + prow + ((t4 * 32 + rg * 8) ^ psw)) = pk;
      }
      ls[qf] += sum;
      // DS pipe is in-order within a wave: reads below see this qf's writes,
      // and the next qf's writes can't pass these reads.
      pb[qf][0] = ld16(Pw + prow + ((rg * 16) ^ psw));
      pb[qf][1] = ld16(Pw + prow + ((64 + rg * 16) ^ psw));
    }

    // PV: O^T[d][q] += V^T x P  (va shared across the 4 q-frags)
    __builtin_amdgcn_s_setprio(1);
#pragma unroll
    for (int fd = 0; fd < 8; ++fd) {
      const int vrow = fd * 16 + cq;
      const int vsw = (vrow & 7) << 4;
      s16x8 va0 = ld16(Vb + vrow * 128 + ((rg * 16) ^ vsw));
      s16x8 va1 = ld16(Vb + vrow * 128 + ((64 + rg * 16) ^ vsw));
#pragma unroll
      for (int qf = 0; qf < 4; ++qf) {
        acc[fd][qf] = MFMA16(va0, pb[qf][0], acc[fd][qf]);
        acc[fd][qf] = MFMA16(va1, pb[qf][1], acc[fd][qf]);
      }
    }
    __builtin_amdgcn_s_setprio(0);

    __syncthreads();   // drains vmcnt (prefetch DMA) + syncs buffer swap
  }

  float ri[4];
#pragma unroll
  for (int qf = 0; qf < 4; ++qf) {
    float s = ls[qf];
    s += __shfl_xor(s, 16); s += __shfl_xor(s, 32);
    ri[qf] = 1.0f / s;
  }

  // O^T -> swizzled LDS transpose (K/V area, dead) -> coalesced global rows
  char* Ow = lds + w * 16384;          // [64 q][256B]
#pragma unroll
  for (int fd = 0; fd < 8; ++fd)
#pragma unroll
    for (int qf = 0; qf < 4; ++qf) {
      const int ql = qf * 16 + cq;
#pragma unroll
      for (int rr = 0; rr < 4; rr += 2) {
        const unsigned int pk = (unsigned)f2b(acc[fd][qf][rr] * ri[qf]) |
                                ((unsigned)f2b(acc[fd][qf][rr + 1] * ri[qf]) << 16);
        const int d0 = fd * 16 + rg * 4 + rr;
        *(unsigned int*)(Ow + ql * 256 + ((d0 * 2) ^ ((ql & 7) << 4))) = pk;
      }
    }
  const int b = bh >> 3, h = bh & 7;
#pragma unroll
  for (int pr = 0; pr < 16; ++pr) {
    const int ql = pr * 4 + rg;
    uint4 ov = *(const uint4*)(Ow + ql * 256 + ((cq * 16) ^ ((ql & 7) << 4)));
    *(uint4*)((char*)Obuf + ((size_t)(b * LN + q0 + ql) * 1024 + h * 128) * 2 + cq * 16) = ov;
  }
}

// ---------------------------------------------------------------------------
extern "C" void kernel_launch(void* const* d_in, const int* in_sizes, int n_in,
                              void* d_out, int out_size, void* d_ws, size_t ws_size,
                              hipStream_t stream)
{
  (void)in_sizes; (void)n_in; (void)out_size; (void)ws_size;
  const float* q  = (const float*)d_in[0];
  const float* k  = (const float*)d_in[1];
  const float* v  = (const float*)d_in[2];
  const float* Wq = (const float*)d_in[3];
  const float* bq = (const float*)d_in[4];
  const float* Wk = (const float*)d_in[5];
  const float* bk = (const float*)d_in[6];
  const float* Wv = (const float*)d_in[7];
  const float* bv = (const float*)d_in[8];
  const float* Wo = (const float*)d_in[9];
  const float* bo = (const float*)d_in[10];

  char* ws = (char*)d_ws;
  size_t off = 0;
  auto alloc = [&](size_t bytes) { char* p = ws + off; off += (bytes + 255) & ~(size_t)255; return p; };
  __hip_bfloat16* qb  = (__hip_bfloat16*)alloc((size_t)MROWS * 128 * 2);
  __hip_bfloat16* kb  = (__hip_bfloat16*)alloc((size_t)MROWS * 128 * 2);
  __hip_bfloat16* vb  = (__hip_bfloat16*)alloc((size_t)MROWS * 128 * 2);
  __hip_bfloat16* Wqt = (__hip_bfloat16*)alloc(1024 * 128 * 2);
  __hip_bfloat16* Wkt = (__hip_bfloat16*)alloc(1024 * 128 * 2);
  __hip_bfloat16* Wvt = (__hip_bfloat16*)alloc(1024 * 128 * 2);
  __hip_bfloat16* Wot = (__hip_bfloat16*)alloc(128 * 1024 * 2);
  __hip_bfloat16* Qh  = (__hip_bfloat16*)alloc((size_t)64 * LN * 128 * 2);
  __hip_bfloat16* Kh  = (__hip_bfloat16*)alloc((size_t)64 * LN * 128 * 2);
  __hip_bfloat16* Vt  = (__hip_bfloat16*)alloc((size_t)64 * LN * 128 * 2);
  __hip_bfloat16* Ob  = (__hip_bfloat16*)alloc((size_t)MROWS * 1024 * 2);

  const float qscale = 1.4426950408889634f / sqrtf(128.0f);  // log2(e)/sqrt(dk)

  cast_kernel<<<8192, 256, 0, stream>>>(q, k, v, Wq, Wk, Wv, Wo,
                                        qb, kb, vb, Wqt, Wkt, Wvt, Wot, qscale);
  qkv_kernel<<<dim3(128, 8, 3), 256, 0, stream>>>(qb, kb, vb, Wqt, Wkt, Wvt,
                                                  bq, bk, bv, Qh, Kh, Vt, qscale);
  attn_kernel<<<512, 256, 0, stream>>>(Qh, Kh, Vt, Ob);
  oproj_kernel<<<dim3(128, 4), 256, 0, stream>>>(Ob, Wot, bo, (float*)d_out, 1024);
}

// Round 16
// 205.658 us; speedup vs baseline: 1.7157x; 1.7157x over previous
//
#include <hip/hip_runtime.h>
#include <hip/hip_bf16.h>
#include <math.h>

// ---------------------------------------------------------------------------
// MHA: out = softmax((q@Wq+bq)(k@Wk+bk)^T / sqrt(dk)) (v@Wv+bv) @ Wo + bo
// B=8 H=8 L=2048 D=128.  FINAL (r14 config, session best 206us):
//   cast(f32->bf16, W transposed, log2e/sqrt(128) folded into Wq/bq)
//   -> fused QKV projection GEMM (3072 blocks, z selects Q/K/V)
//   -> flash attention v8: 4 waves x 32q full-KV, KVBLK=64 K+V LDS dbuf,
//      2 indep blocks/CU, fixed-offset softmax (159us, ~862 TF = plain-HIP
//      16x16-structure plateau)
//   -> out-proj GEMM (512 blocks)
// [Session laws: launch_bounds 2nd arg X => X waves/EU residency AND VGPR
//  cap ~256/X (X=1:~512, X=2:128(r15), X=4:64(r3/r11)).  acc[8][2]=64 VGPR.
//  Escape routes measured-blocked: r6 kv-split, r7 V-from-global, r9 fat-
//  waves@1w/SIMD, r10/r11 KVBLK=32, r12 counted vmcnt, r15 fat-waves@X=2
//  (128-cap spills).]
// ---------------------------------------------------------------------------

typedef __attribute__((ext_vector_type(8))) short s16x8;   // 8 bf16
typedef __attribute__((ext_vector_type(4))) short s16x4;   // 4 bf16
typedef __attribute__((ext_vector_type(4))) float f32x4;

#define MFMA16(a, b, c) __builtin_amdgcn_mfma_f32_16x16x32_bf16((a), (b), (c), 0, 0, 0)

static constexpr int HN = 8, LN = 2048;
static constexpr int MROWS = 16384;

static __device__ __forceinline__ unsigned short f2b(float f) {
  __hip_bfloat16 h = __float2bfloat16(f);
  union { __hip_bfloat16 h; unsigned short u; } cv;
  cv.h = h;
  return cv.u;
}

static __device__ __forceinline__ s16x8 ld16(const void* p) {
  uint4 t = *(const uint4*)p;
  return __builtin_bit_cast(s16x8, t);
}

// async global->LDS, 16B per lane; LDS dest = wave-uniform base + lane*16
static __device__ __forceinline__ void gload16(const void* g, void* l) {
  __builtin_amdgcn_global_load_lds(
      (const __attribute__((address_space(1))) unsigned int*)g,
      (__attribute__((address_space(3))) unsigned int*)l, 16, 0, 0);
}

static __device__ __forceinline__ unsigned cvt_pk(float lo, float hi) {
  unsigned r;                       // r = [bf16(lo) | bf16(hi)<<16]
  asm("v_cvt_pk_bf16_f32 %0, %1, %2" : "=v"(r) : "v"(lo), "v"(hi));
  return r;
}

static __device__ __forceinline__ float fexp2(float x) {
  float r;
  asm("v_exp_f32 %0, %1" : "=v"(r) : "v"(x));
  return r;
}

// ---------------------------------------------------------------------------
// Kernel 1: casts + weight transposes.
// ---------------------------------------------------------------------------
__global__ __launch_bounds__(256) void cast_kernel(
    const float* __restrict__ q, const float* __restrict__ k,
    const float* __restrict__ v, const float* __restrict__ Wq,
    const float* __restrict__ Wk, const float* __restrict__ Wv,
    const float* __restrict__ Wo,
    __hip_bfloat16* __restrict__ qb, __hip_bfloat16* __restrict__ kb,
    __hip_bfloat16* __restrict__ vb, __hip_bfloat16* __restrict__ Wqt,
    __hip_bfloat16* __restrict__ Wkt, __hip_bfloat16* __restrict__ Wvt,
    __hip_bfloat16* __restrict__ Wot, float qscale)
{
  const int bid = blockIdx.x, tid = threadIdx.x;
  if (bid < 6144) {
    const int idx4 = bid * 256 + tid;
    const int arr  = idx4 >> 19;
    const int off4 = idx4 & ((1 << 19) - 1);
    const float* src = (arr == 0) ? q : (arr == 1) ? k : v;
    __hip_bfloat16* dst = (arr == 0) ? qb : (arr == 1) ? kb : vb;
    float4 ld = ((const float4*)src)[off4];
    s16x4 pk;
    pk[0] = (short)f2b(ld.x); pk[1] = (short)f2b(ld.y);
    pk[2] = (short)f2b(ld.z); pk[3] = (short)f2b(ld.w);
    ((s16x4*)dst)[off4] = pk;
  } else {
    const int t = (bid - 6144) * 256 + tid;
    const int which = t >> 17;
    const int i = t & ((1 << 17) - 1);
    if (which < 3) {
      const int n = i >> 7, kk = i & 127;
      const float* W = (which == 0) ? Wq : (which == 1) ? Wk : Wv;
      __hip_bfloat16* Wt = (which == 0) ? Wqt : (which == 1) ? Wkt : Wvt;
      float val = W[kk * 1024 + n];
      if (which == 0) val *= qscale;
      Wt[n * 128 + kk] = __float2bfloat16(val);
    } else {
      const int n = i >> 10, kk = i & 1023;
      Wot[n * 1024 + kk] = __float2bfloat16(Wo[kk * 128 + n]);
    }
  }
}

// ---------------------------------------------------------------------------
// Kernel 2a: fused QKV projection GEMM (one launch, blockIdx.z selects).
// C[M,1024] = A[M,128] @ Btr[1024,128]^T (+bias).  128x128 tile, BK=64,
// 4 waves (2x2), gload_lds dbuf.  z=0: Q -> [b][h][l][d] (bias*qscale);
// z=1: K -> [b][h][l][d]; z=2: V -> [b][h][d][l] (transposed).
// ---------------------------------------------------------------------------
__global__ __launch_bounds__(256) void qkv_kernel(
    const __hip_bfloat16* __restrict__ qb, const __hip_bfloat16* __restrict__ kb,
    const __hip_bfloat16* __restrict__ vb,
    const __hip_bfloat16* __restrict__ Wqt, const __hip_bfloat16* __restrict__ Wkt,
    const __hip_bfloat16* __restrict__ Wvt,
    const float* __restrict__ bq, const float* __restrict__ bk,
    const float* __restrict__ bv,
    __hip_bfloat16* __restrict__ Qh, __hip_bfloat16* __restrict__ Kh,
    __hip_bfloat16* __restrict__ Vt, float qscale)
{
  constexpr int NF = 4, K = 128;
  constexpr int BUFB = (4 + NF) * 4096;        // A 16KB + B 16KB
  __shared__ char lds[2 * BUFB];

  const int z = blockIdx.z;
  const __hip_bfloat16* A   = (z == 0) ? qb  : (z == 1) ? kb  : vb;
  const __hip_bfloat16* Btr = (z == 0) ? Wqt : (z == 1) ? Wkt : Wvt;
  const float* bias         = (z == 0) ? bq  : (z == 1) ? bk  : bv;
  __hip_bfloat16* outp      = (z == 0) ? Qh  : (z == 1) ? Kh  : Vt;
  const float bias_scale    = (z == 0) ? qscale : 1.0f;
  const bool vmode          = (z == 2);

  const int tid = threadIdx.x;
  const int l = tid & 63, w = tid >> 6;        // 4 waves
  const int wr = w >> 1, wc = w & 1;
  const int m0 = blockIdx.x * 128, n0 = blockIdx.y * 128;
  const int cq = l & 15, rg = l >> 4;
  const int lrow8 = l >> 3, lcol8 = l & 7;
  const int swz8 = (lcol8 ^ lrow8) * 8;        // inverse-swizzle (elems)

  f32x4 acc[4][NF] = {};

  auto stage = [&](int bb, int k0) {
    char* Ab = lds + bb * BUFB;
    char* Bb = Ab + 16384;
#pragma unroll
    for (int c = 0; c < 4; ++c) {
      const int ca = w * 4 + c;
      gload16(A + (size_t)(m0 + ca * 8 + lrow8) * K + k0 + swz8, Ab + ca * 1024);
    }
#pragma unroll
    for (int c = 0; c < NF; ++c) {
      const int cb = w * NF + c;
      gload16(Btr + (size_t)(n0 + cb * 8 + lrow8) * K + k0 + swz8, Bb + cb * 1024);
    }
  };

  stage(0, 0);
  __syncthreads();

  for (int kt = 0; kt < 2; ++kt) {
    const int cur = kt & 1;
    if (kt == 0) stage(1, 64);
    char* As = lds + cur * BUFB;
    char* Bs = As + 16384;
#pragma unroll
    for (int ks = 0; ks < 2; ++ks) {
      s16x8 af[4], bf[NF];
#pragma unroll
      for (int mf = 0; mf < 4; ++mf) {
        const int arow = wr * 64 + mf * 16 + cq;
        af[mf] = ld16(As + arow * 128 + ((ks * 64 + rg * 16) ^ ((arow & 7) << 4)));
      }
#pragma unroll
      for (int nf = 0; nf < NF; ++nf) {
        const int brow = wc * (NF * 16) + nf * 16 + cq;
        bf[nf] = ld16(Bs + brow * 128 + ((ks * 64 + rg * 16) ^ ((brow & 7) << 4)));
      }
#pragma unroll
      for (int mf = 0; mf < 4; ++mf)
#pragma unroll
        for (int nf = 0; nf < NF; ++nf)
          acc[mf][nf] = MFMA16(af[mf], bf[nf], acc[mf][nf]);
    }
    __syncthreads();
  }

  // epilogue: C/D layout col = lane&15, row = (lane>>4)*4 + r
#pragma unroll
  for (int nf = 0; nf < NF; ++nf) {
    const int gn = n0 + wc * (NF * 16) + nf * 16 + cq;
    const float bv_ = bias[gn] * bias_scale;
    const int h = gn >> 7, d = gn & 127;
#pragma unroll
    for (int mf = 0; mf < 4; ++mf) {
      const int gm0 = m0 + wr * 64 + mf * 16 + rg * 4;
      const f32x4 a = acc[mf][nf];
      if (!vmode) {
#pragma unroll
        for (int r = 0; r < 4; ++r) {
          const int gm = gm0 + r;
          const int b = gm >> 11, lr = gm & (LN - 1);
          outp[((size_t)(b * HN + h) * LN + lr) * 128 + d] = __float2bfloat16(a[r] + bv_);
        }
      } else {
        const int b = gm0 >> 11, kv = gm0 & (LN - 1);
        s16x4 pk;
#pragma unroll
        for (int r = 0; r < 4; ++r) pk[r] = (short)f2b(a[r] + bv_);
        *(s16x4*)(outp + ((size_t)(b * HN + h) * 128 + d) * LN + kv) = pk;
      }
    }
  }
}

// ---------------------------------------------------------------------------
// Kernel 2b: out-proj GEMM  C[M,128] = A[M,1024] @ Btr[128,1024]^T + bo (f32).
// NF=1, (128,4) grid = 512 blocks.  gload_lds dbuf.
// ---------------------------------------------------------------------------
__global__ __launch_bounds__(256) void oproj_kernel(
    const __hip_bfloat16* __restrict__ A, const __hip_bfloat16* __restrict__ Btr,
    const float* __restrict__ bias, float* __restrict__ outp, int K)
{
  constexpr int NF = 1;
  constexpr int BUFB = (4 + NF) * 4096;        // A 16KB + B 4KB
  __shared__ char lds[2 * BUFB];

  const int tid = threadIdx.x;
  const int l = tid & 63, w = tid >> 6;
  const int wr = w >> 1, wc = w & 1;
  const int m0 = blockIdx.x * 128, n0 = blockIdx.y * 32;
  const int cq = l & 15, rg = l >> 4;
  const int lrow8 = l >> 3, lcol8 = l & 7;
  const int swz8 = (lcol8 ^ lrow8) * 8;
  const int nk = K >> 6;

  f32x4 acc[4][NF] = {};

  auto stage = [&](int bb, int k0) {
    char* Ab = lds + bb * BUFB;
    char* Bb = Ab + 16384;
#pragma unroll
    for (int c = 0; c < 4; ++c) {
      const int ca = w * 4 + c;
      gload16(A + (size_t)(m0 + ca * 8 + lrow8) * K + k0 + swz8, Ab + ca * 1024);
    }
#pragma unroll
    for (int c = 0; c < NF; ++c) {
      const int cb = w * NF + c;
      gload16(Btr + (size_t)(n0 + cb * 8 + lrow8) * K + k0 + swz8, Bb + cb * 1024);
    }
  };

  stage(0, 0);
  __syncthreads();

  for (int kt = 0; kt < nk; ++kt) {
    const int cur = kt & 1;
    if (kt + 1 < nk) stage(cur ^ 1, (kt + 1) << 6);
    char* As = lds + cur * BUFB;
    char* Bs = As + 16384;
#pragma unroll
    for (int ks = 0; ks < 2; ++ks) {
      s16x8 af[4], bf[NF];
#pragma unroll
      for (int mf = 0; mf < 4; ++mf) {
        const int arow = wr * 64 + mf * 16 + cq;
        af[mf] = ld16(As + arow * 128 + ((ks * 64 + rg * 16) ^ ((arow & 7) << 4)));
      }
#pragma unroll
      for (int nf = 0; nf < NF; ++nf) {
        const int brow = wc * (NF * 16) + nf * 16 + cq;
        bf[nf] = ld16(Bs + brow * 128 + ((ks * 64 + rg * 16) ^ ((brow & 7) << 4)));
      }
#pragma unroll
      for (int mf = 0; mf < 4; ++mf)
#pragma unroll
        for (int nf = 0; nf < NF; ++nf)
          acc[mf][nf] = MFMA16(af[mf], bf[nf], acc[mf][nf]);
    }
    __syncthreads();
  }

#pragma unroll
  for (int nf = 0; nf < NF; ++nf) {
    const int gn = n0 + wc * (NF * 16) + nf * 16 + cq;
    const float bv_ = bias[gn];
#pragma unroll
    for (int mf = 0; mf < 4; ++mf) {
      const int gm0 = m0 + wr * 64 + mf * 16 + rg * 4;
      const f32x4 a = acc[mf][nf];
#pragma unroll
      for (int r = 0; r < 4; ++r)
        outp[(size_t)(gm0 + r) * 128 + gn] = a[r] + bv_;
    }
  }
}

// ---------------------------------------------------------------------------
// Kernel 3: flash attention v8 (r8/r13/r14 best).
// Block = 4 waves (256 thr) = 128 q of one (b,h); wave = 32 q x full KVBLK=64.
// K [2][64][256B] + V^T [2][128][128B] dbuf via global_load_lds (linear dest,
// inverse-swizzled source, XOR-swizzled reads).  P = exp2(S) directly (no
// max tracking: softmax shift-invariance; scores pre-scaled to log2 domain).
// P via wave-local swizzled LDS round-trip.  72KB LDS -> 2 indep blocks/CU.
// ---------------------------------------------------------------------------
__global__ __launch_bounds__(256, 2) void attn_kernel(
    const __hip_bfloat16* __restrict__ Qh, const __hip_bfloat16* __restrict__ Kh,
    const __hip_bfloat16* __restrict__ Vt, __hip_bfloat16* __restrict__ Obuf)
{
  __shared__ char lds[73728];          // K 2x16K | V 2x16K | P 4x2K
  char* Ks = lds;                      // [2][64 rows][256B]
  char* Vs = lds + 32768;              // [2][128 rows][128B]

  // bijective XCD swizzle: 1024 blocks = 8 xcd x 8 bh x 16 qtiles
  const int x = blockIdx.x;
  const int xcd = x & 7, ii = x >> 3;
  const int bh = xcd * 8 + (ii >> 4);
  const int qt = ii & 15;

  const int tid = threadIdx.x, l = tid & 63, w = tid >> 6;   // w in [0,4)
  const int cq = l & 15, rg = l >> 4;
  const int q0 = qt * 128 + w * 32;

  char* Pw = lds + 65536 + w * 2048;   // per-wave P^T: [16 q][128B] (swz)

  const char* Qc = (const char*)(Qh + (size_t)bh * LN * 128);
  const char* Kc = (const char*)(Kh + (size_t)bh * LN * 128);
  const char* Vc = (const char*)(Vt + (size_t)bh * 128 * LN);

  // Q fragments in registers (B-operand of swapped QK^T)
  s16x8 qreg[2][4];
#pragma unroll
  for (int qf = 0; qf < 2; ++qf)
#pragma unroll
    for (int ks = 0; ks < 4; ++ks)
      qreg[qf][ks] = ld16(Qc + (size_t)(q0 + qf * 16 + cq) * 256 + ks * 64 + rg * 16);

  // staging source offsets (inverse-swizzled); LDS dests linear (lane*16)
  int kgoff[4], vgoff[4];
#pragma unroll
  for (int j = 0; j < 4; ++j) {
    const int ck = w * 256 + j * 64 + l;               // chunk in [0,1024)
    const int kr = ck >> 4, kc = ck & 15;              // K: rows of 256B
    kgoff[j] = kr * 256 + ((kc ^ (kr & 7)) * 16);
    const int vr = ck >> 3, vc = ck & 7;               // V: rows of 128B
    vgoff[j] = vr * 4096 + ((vc ^ (vr & 7)) * 16);     // global row stride 4KB
  }

  auto stageKV = [&](int buf, int t) {
    const char* kg = Kc + (size_t)t * 16384;
    const char* vg = Vc + (size_t)t * 128;
#pragma unroll
    for (int j = 0; j < 4; ++j) {
      gload16(kg + kgoff[j], Ks + buf * 16384 + w * 4096 + j * 1024);
      gload16(vg + vgoff[j], Vs + buf * 16384 + w * 4096 + j * 1024);
    }
  };

  f32x4 acc[8][2] = {};
  float ls0 = 0.f, ls1 = 0.f;

  stageKV(0, 0);
  __syncthreads();

#pragma unroll 2
  for (int t = 0; t < 32; ++t) {
    const int cur = t & 1;
    if (t < 31) stageKV(cur ^ 1, t + 1);          // async prefetch t+1
    char* Kb = Ks + cur * 16384;
    char* Vb = Vs + cur * 16384;

    // QK^T: st[qf][t4], kv = t4*16 + rg*4 + r, q = qf*16 + cq
    f32x4 st[2][4] = {};
    __builtin_amdgcn_s_setprio(1);
#pragma unroll
    for (int t4 = 0; t4 < 4; ++t4) {
      const int row = t4 * 16 + cq;
      const int rsw = (row & 7) << 4;
      s16x8 kf[4];
#pragma unroll
      for (int ks = 0; ks < 4; ++ks)
        kf[ks] = ld16(Kb + row * 256 + ((ks * 64 + rg * 16) ^ rsw));
#pragma unroll
      for (int ks = 0; ks < 4; ++ks) {
        st[0][t4] = MFMA16(kf[ks], qreg[0][ks], st[0][t4]);
        st[1][t4] = MFMA16(kf[ks], qreg[1][ks], st[1][t4]);
      }
    }
    __builtin_amdgcn_s_setprio(0);

    // P = exp2(S) (fixed-offset softmax; no max tracking) -> swizzled LDS
    s16x8 pb[2][2];
#pragma unroll
    for (int qf = 0; qf < 2; ++qf) {
      float sum = 0.f;
      const int prow = cq * 128;
      const int psw = (cq & 7) << 4;
#pragma unroll
      for (int t4 = 0; t4 < 4; ++t4) {
        const float e0 = fexp2(st[qf][t4][0]);
        const float e1 = fexp2(st[qf][t4][1]);
        const float e2 = fexp2(st[qf][t4][2]);
        const float e3 = fexp2(st[qf][t4][3]);
        sum += (e0 + e1) + (e2 + e3);
        uint2 pk;
        pk.x = cvt_pk(e0, e1);
        pk.y = cvt_pk(e2, e3);
        *(uint2*)(Pw + prow + ((t4 * 32 + rg * 8) ^ psw)) = pk;
      }
      if (qf) ls1 += sum; else ls0 += sum;
      pb[qf][0] = ld16(Pw + prow + ((rg * 16) ^ psw));
      pb[qf][1] = ld16(Pw + prow + ((64 + rg * 16) ^ psw));
    }

    // PV: O^T[d][q] += V^T x P
    __builtin_amdgcn_s_setprio(1);
#pragma unroll
    for (int fd = 0; fd < 8; ++fd) {
      const int vrow = fd * 16 + cq;
      const int vsw = (vrow & 7) << 4;
      s16x8 va0 = ld16(Vb + vrow * 128 + ((rg * 16) ^ vsw));
      s16x8 va1 = ld16(Vb + vrow * 128 + ((64 + rg * 16) ^ vsw));
      acc[fd][0] = MFMA16(va0, pb[0][0], acc[fd][0]);
      acc[fd][0] = MFMA16(va1, pb[0][1], acc[fd][0]);
      acc[fd][1] = MFMA16(va0, pb[1][0], acc[fd][1]);
      acc[fd][1] = MFMA16(va1, pb[1][1], acc[fd][1]);
    }
    __builtin_amdgcn_s_setprio(0);

    __syncthreads();   // drains vmcnt (prefetch DMA) + syncs buffer swap
  }

  ls0 += __shfl_xor(ls0, 16); ls0 += __shfl_xor(ls0, 32);
  ls1 += __shfl_xor(ls1, 16); ls1 += __shfl_xor(ls1, 32);
  const float ri0 = 1.0f / ls0, ri1 = 1.0f / ls1;

  // O^T -> swizzled LDS transpose (K area, dead) -> coalesced global rows
  char* Ow = lds + w * 8192;           // [32 q][256B]
#pragma unroll
  for (int fd = 0; fd < 8; ++fd)
#pragma unroll
    for (int qf = 0; qf < 2; ++qf) {
      const float ri = qf ? ri1 : ri0;
      const int ql = qf * 16 + cq;
#pragma unroll
      for (int rr = 0; rr < 4; rr += 2) {
        const unsigned int pk = (unsigned)f2b(acc[fd][qf][rr] * ri) |
                                ((unsigned)f2b(acc[fd][qf][rr + 1] * ri) << 16);
        const int d0 = fd * 16 + rg * 4 + rr;
        *(unsigned int*)(Ow + ql * 256 + ((d0 * 2) ^ ((ql & 7) << 4))) = pk;
      }
    }
  const int b = bh >> 3, h = bh & 7;
#pragma unroll
  for (int pr = 0; pr < 8; ++pr) {
    const int ql = pr * 4 + rg;
    uint4 ov = *(const uint4*)(Ow + ql * 256 + ((cq * 16) ^ ((ql & 7) << 4)));
    *(uint4*)((char*)Obuf + ((size_t)(b * LN + q0 + ql) * 1024 + h * 128) * 2 + cq * 16) = ov;
  }
}

// ---------------------------------------------------------------------------
extern "C" void kernel_launch(void* const* d_in, const int* in_sizes, int n_in,
                              void* d_out, int out_size, void* d_ws, size_t ws_size,
                              hipStream_t stream)
{
  (void)in_sizes; (void)n_in; (void)out_size; (void)ws_size;
  const float* q  = (const float*)d_in[0];
  const float* k  = (const float*)d_in[1];
  const float* v  = (const float*)d_in[2];
  const float* Wq = (const float*)d_in[3];
  const float* bq = (const float*)d_in[4];
  const float* Wk = (const float*)d_in[5];
  const float* bk = (const float*)d_in[6];
  const float* Wv = (const float*)d_in[7];
  const float* bv = (const float*)d_in[8];
  const float* Wo = (const float*)d_in[9];
  const float* bo = (const float*)d_in[10];

  char* ws = (char*)d_ws;
  size_t off = 0;
  auto alloc = [&](size_t bytes) { char* p = ws + off; off += (bytes + 255) & ~(size_t)255; return p; };
  __hip_bfloat16* qb  = (__hip_bfloat16*)alloc((size_t)MROWS * 128 * 2);
  __hip_bfloat16* kb  = (__hip_bfloat16*)alloc((size_t)MROWS * 128 * 2);
  __hip_bfloat16* vb  = (__hip_bfloat16*)alloc((size_t)MROWS * 128 * 2);
  __hip_bfloat16* Wqt = (__hip_bfloat16*)alloc(1024 * 128 * 2);
  __hip_bfloat16* Wkt = (__hip_bfloat16*)alloc(1024 * 128 * 2);
  __hip_bfloat16* Wvt = (__hip_bfloat16*)alloc(1024 * 128 * 2);
  __hip_bfloat16* Wot = (__hip_bfloat16*)alloc(128 * 1024 * 2);
  __hip_bfloat16* Qh  = (__hip_bfloat16*)alloc((size_t)64 * LN * 128 * 2);
  __hip_bfloat16* Kh  = (__hip_bfloat16*)alloc((size_t)64 * LN * 128 * 2);
  __hip_bfloat16* Vt  = (__hip_bfloat16*)alloc((size_t)64 * LN * 128 * 2);
  __hip_bfloat16* Ob  = (__hip_bfloat16*)alloc((size_t)MROWS * 1024 * 2);

  const float qscale = 1.4426950408889634f / sqrtf(128.0f);  // log2(e)/sqrt(dk)

  cast_kernel<<<8192, 256, 0, stream>>>(q, k, v, Wq, Wk, Wv, Wo,
                                        qb, kb, vb, Wqt, Wkt, Wvt, Wot, qscale);
  qkv_kernel<<<dim3(128, 8, 3), 256, 0, stream>>>(qb, kb, vb, Wqt, Wkt, Wvt,
                                                  bq, bk, bv, Qh, Kh, Vt, qscale);
  attn_kernel<<<1024, 256, 0, stream>>>(Qh, Kh, Vt, Ob);
  oproj_kernel<<<dim3(128, 4), 256, 0, stream>>>(Ob, Wot, bo, (float*)d_out, 1024);
}